// Round 1
// baseline (634.615 us; speedup 1.0000x reference)
//
#include <hip/hip_runtime.h>

#define IN_CH 1024
#define INTER 512
#define NEXP  128
#define TPE   512

typedef __bf16 bf16x8  __attribute__((ext_vector_type(8)));
typedef __bf16 bf16x4v __attribute__((ext_vector_type(4)));
typedef float  f32x4   __attribute__((ext_vector_type(4)));

// ---------------- Kernel A: h = silu(x@w1^T + b1) * (x@w3^T + b3) ------------
// Grid: 128 experts * 16 tiles (4x4 over [512 tok x 512 f]); 256 threads.
// BM=BN=128, BK=64. LDS XOR-swizzled (16B chunk ^ (row&7)) for conflict-free
// ds_read_b128 on MFMA fragment reads.
__global__ __launch_bounds__(256) void moe_h_kernel(
    const float* __restrict__ x, const int* __restrict__ idxs,
    const float* __restrict__ w1w, const float* __restrict__ w1b,
    const float* __restrict__ w3w, const float* __restrict__ w3b,
    __bf16* __restrict__ hbuf)
{
  __shared__ __align__(16) ushort sA[128*64];
  __shared__ __align__(16) ushort sB1[128*64];
  __shared__ __align__(16) ushort sB3[128*64];

  const int blk = blockIdx.x;
  const int e   = blk >> 4;
  const int tl  = blk & 15;
  const int tm  = tl >> 2, tn = tl & 3;

  const int tid  = threadIdx.x;
  const int lane = tid & 63;
  const int wid  = tid >> 6;
  const int wm   = wid >> 1, wn = wid & 1;

  // staging decomposition: 2048 float4-chunks per tile; thread t handles
  // rows r0+16i (i=0..7), float4-col c4. Coalesced 256B per 16 threads.
  const int r0 = tid >> 4;   // 0..15
  const int c4 = tid & 15;   // 0..15 (64 floats per row = 16 float4)

  // token gather pointers (row set fixed across K iterations)
  const float* aptr[8];
#pragma unroll
  for (int i = 0; i < 8; ++i) {
    const int r   = r0 + 16*i;
    const int tok = idxs[e*TPE + tm*128 + r];
    aptr[i] = x + (size_t)tok*IN_CH + (c4<<2);
  }
  const float* b1p = w1w + ((size_t)e*INTER + tn*128 + r0)*IN_CH + (c4<<2);
  const float* b3p = w3w + ((size_t)e*INTER + tn*128 + r0)*IN_CH + (c4<<2);

  // swizzled LDS write offset (ushort units); (r&7) constant across i
  const int swz = ((((c4>>1) ^ (r0&7))<<3) | ((c4&1)<<2));

  f32x4 acc1[4][4], acc3[4][4];
#pragma unroll
  for (int a = 0; a < 4; ++a)
#pragma unroll
    for (int b = 0; b < 4; ++b) {
      acc1[a][b] = (f32x4){0.f,0.f,0.f,0.f};
      acc3[a][b] = (f32x4){0.f,0.f,0.f,0.f};
    }

  for (int kt = 0; kt < IN_CH/64; ++kt) {
    const int kof = kt*64;
#pragma unroll
    for (int i = 0; i < 8; ++i) {
      const float4 v = *(const float4*)(aptr[i] + kof);
      bf16x4v b; b[0]=(__bf16)v.x; b[1]=(__bf16)v.y; b[2]=(__bf16)v.z; b[3]=(__bf16)v.w;
      *(bf16x4v*)&sA[(r0 + 16*i)*64 + swz] = b;
    }
#pragma unroll
    for (int i = 0; i < 8; ++i) {
      const float4 v = *(const float4*)(b1p + (size_t)(16*i)*IN_CH + kof);
      bf16x4v b; b[0]=(__bf16)v.x; b[1]=(__bf16)v.y; b[2]=(__bf16)v.z; b[3]=(__bf16)v.w;
      *(bf16x4v*)&sB1[(r0 + 16*i)*64 + swz] = b;
    }
#pragma unroll
    for (int i = 0; i < 8; ++i) {
      const float4 v = *(const float4*)(b3p + (size_t)(16*i)*IN_CH + kof);
      bf16x4v b; b[0]=(__bf16)v.x; b[1]=(__bf16)v.y; b[2]=(__bf16)v.z; b[3]=(__bf16)v.w;
      *(bf16x4v*)&sB3[(r0 + 16*i)*64 + swz] = b;
    }
    __syncthreads();

#pragma unroll
    for (int ks = 0; ks < 2; ++ks) {
      bf16x8 af[4], bq[4], bt[4];
      const int k8 = (ks<<2) + (lane>>4);
#pragma unroll
      for (int mi = 0; mi < 4; ++mi) {
        const int r = wm*64 + mi*16 + (lane&15);
        af[mi] = *(const bf16x8*)&sA[r*64 + ((k8 ^ (r&7))<<3)];
      }
#pragma unroll
      for (int ni = 0; ni < 4; ++ni) {
        const int r   = wn*64 + ni*16 + (lane&15);
        const int off = r*64 + ((k8 ^ (r&7))<<3);
        bq[ni] = *(const bf16x8*)&sB1[off];
        bt[ni] = *(const bf16x8*)&sB3[off];
      }
#pragma unroll
      for (int mi = 0; mi < 4; ++mi)
#pragma unroll
        for (int ni = 0; ni < 4; ++ni) {
          acc1[mi][ni] = __builtin_amdgcn_mfma_f32_16x16x32_bf16(af[mi], bq[ni], acc1[mi][ni], 0, 0, 0);
          acc3[mi][ni] = __builtin_amdgcn_mfma_f32_16x16x32_bf16(af[mi], bt[ni], acc3[mi][ni], 0, 0, 0);
        }
    }
    __syncthreads();
  }

  // epilogue: bias + SwiGLU, store bf16 h tile
  const int rowbase = tm*128 + wm*64;
  const int colbase = tn*128 + wn*64;
#pragma unroll
  for (int ni = 0; ni < 4; ++ni) {
    const int fc = colbase + ni*16 + (lane&15);
    const float b1v = w1b[e*INTER + fc];
    const float b3v = w3b[e*INTER + fc];
#pragma unroll
    for (int mi = 0; mi < 4; ++mi) {
#pragma unroll
      for (int j = 0; j < 4; ++j) {
        const int rl = rowbase + mi*16 + ((lane>>4)<<2) + j;
        const float h1 = acc1[mi][ni][j] + b1v;
        const float h3 = acc3[mi][ni][j] + b3v;
        const float s  = h1 / (1.0f + __expf(-h1));
        hbuf[((size_t)e*TPE + rl)*INTER + fc] = (__bf16)(s * h3);
      }
    }
  }
}

// ---------------- Kernel B: out = h @ w2^T + b2, scattered via idxs ----------
// Grid: 128 experts * 32 tiles (4x8 over [512 tok x 1024 ch]); 256 threads.
__global__ __launch_bounds__(256) void moe_out_kernel(
    const __bf16* __restrict__ hbuf, const float* __restrict__ w2w,
    const float* __restrict__ w2b, const int* __restrict__ idxs,
    float* __restrict__ out)
{
  __shared__ __align__(16) ushort sA[128*64];
  __shared__ __align__(16) ushort sB[128*64];

  const int blk = blockIdx.x;
  const int e   = blk >> 5;
  const int tl  = blk & 31;
  const int tm  = tl >> 3, tn = tl & 7;

  const int tid  = threadIdx.x;
  const int lane = tid & 63;
  const int wid  = tid >> 6;
  const int wm   = wid >> 1, wn = wid & 1;

  // A (h, already bf16): 1024 x 16B chunks; thread t: rows rA+32i, chunk c8
  const int rA   = tid >> 3;          // 0..31
  const int c8   = tid & 7;           // 0..7 (64 bf16 = 8 chunks of 8)
  const int swzA = ((c8 ^ (rA&7))<<3);
  const __bf16* ap = hbuf + ((size_t)e*TPE + tm*128 + rA)*INTER + (c8<<3);

  // B (w2, fp32 -> bf16)
  const int r0   = tid >> 4;
  const int c4   = tid & 15;
  const int swzB = ((((c4>>1) ^ (r0&7))<<3) | ((c4&1)<<2));
  const float* bp = w2w + ((size_t)e*IN_CH + tn*128 + r0)*INTER + (c4<<2);

  f32x4 acc[4][4];
#pragma unroll
  for (int a = 0; a < 4; ++a)
#pragma unroll
    for (int b = 0; b < 4; ++b) acc[a][b] = (f32x4){0.f,0.f,0.f,0.f};

  for (int kt = 0; kt < INTER/64; ++kt) {
    const int kof = kt*64;
#pragma unroll
    for (int i = 0; i < 4; ++i) {
      const uint4 v = *(const uint4*)(ap + (size_t)(32*i)*INTER + kof);
      *(uint4*)&sA[(rA + 32*i)*64 + swzA] = v;
    }
#pragma unroll
    for (int i = 0; i < 8; ++i) {
      const float4 v = *(const float4*)(bp + (size_t)(16*i)*INTER + kof);
      bf16x4v b; b[0]=(__bf16)v.x; b[1]=(__bf16)v.y; b[2]=(__bf16)v.z; b[3]=(__bf16)v.w;
      *(bf16x4v*)&sB[(r0 + 16*i)*64 + swzB] = b;
    }
    __syncthreads();

#pragma unroll
    for (int ks = 0; ks < 2; ++ks) {
      bf16x8 af[4], bf[4];
      const int k8 = (ks<<2) + (lane>>4);
#pragma unroll
      for (int mi = 0; mi < 4; ++mi) {
        const int r = wm*64 + mi*16 + (lane&15);
        af[mi] = *(const bf16x8*)&sA[r*64 + ((k8 ^ (r&7))<<3)];
      }
#pragma unroll
      for (int ni = 0; ni < 4; ++ni) {
        const int r = wn*64 + ni*16 + (lane&15);
        bf[ni] = *(const bf16x8*)&sB[r*64 + ((k8 ^ (r&7))<<3)];
      }
#pragma unroll
      for (int mi = 0; mi < 4; ++mi)
#pragma unroll
        for (int ni = 0; ni < 4; ++ni)
          acc[mi][ni] = __builtin_amdgcn_mfma_f32_16x16x32_bf16(af[mi], bf[ni], acc[mi][ni], 0, 0, 0);
    }
    __syncthreads();
  }

  // epilogue: bias + scatter to original token positions (fp32)
  const int rowbase = tm*128 + wm*64;
  const int colbase = tn*128 + wn*64;
  float b2v[4];
#pragma unroll
  for (int ni = 0; ni < 4; ++ni)
    b2v[ni] = w2b[e*IN_CH + colbase + ni*16 + (lane&15)];
#pragma unroll
  for (int mi = 0; mi < 4; ++mi) {
#pragma unroll
    for (int j = 0; j < 4; ++j) {
      const int rl  = rowbase + mi*16 + ((lane>>4)<<2) + j;
      const int tok = idxs[e*TPE + rl];
      float* orow = out + (size_t)tok*IN_CH;
#pragma unroll
      for (int ni = 0; ni < 4; ++ni)
        orow[colbase + ni*16 + (lane&15)] = acc[mi][ni][j] + b2v[ni];
    }
  }
}

extern "C" void kernel_launch(void* const* d_in, const int* in_sizes, int n_in,
                              void* d_out, int out_size, void* d_ws, size_t ws_size,
                              hipStream_t stream) {
  const float* x    = (const float*)d_in[0];
  const int*   idxs = (const int*)d_in[1];
  const float* w1w  = (const float*)d_in[2];
  const float* w1b  = (const float*)d_in[3];
  const float* w2w  = (const float*)d_in[4];
  const float* w2b  = (const float*)d_in[5];
  const float* w3w  = (const float*)d_in[6];
  const float* w3b  = (const float*)d_in[7];
  float*  out  = (float*)d_out;
  __bf16* hbuf = (__bf16*)d_ws;   // 128*512*512 bf16 = 64 MB intermediate

  moe_h_kernel<<<dim3(NEXP*16), dim3(256), 0, stream>>>(x, idxs, w1w, w1b, w3w, w3b, hbuf);
  moe_out_kernel<<<dim3(NEXP*32), dim3(256), 0, stream>>>(hbuf, w2w, w2b, idxs, out);
}